// Round 7
// baseline (1358.633 us; speedup 1.0000x reference)
//
#include <hip/hip_runtime.h>
#include <math.h>

#define T_ 16
#define N_ 20000
#define E_ 320000
#define EN_ (E_ + N_)
#define B_ 16
#define RPF 32
#define RNODES ((N_ + RPF - 1) / RPF)   // 625 nodes per range

__device__ __forceinline__ float lrelu(float v) { return v >= 0.f ? v : 0.2f * v; }
__device__ __forceinline__ float elu(float v) { return v > 0.f ? v : expm1f(v); }
__device__ __forceinline__ float rdlane(float v, int k) {
    return __uint_as_float(__builtin_amdgcn_readlane(__float_as_uint(v), k));
}

__device__ __forceinline__ void frame_map(int bid, int* frame, int* local) {
    int blk = bid >> 3;
    *frame = (bid & 7) * 2 + (blk & 1);
    *local = blk >> 1;
}

// ---- layer 1: h1 = x @ W1 (7->64), per-head attention dots ----
__global__ __launch_bounds__(256) void k_h1(
    const float* __restrict__ x, const float* __restrict__ W1,
    const float* __restrict__ as1, const float* __restrict__ ad1,
    float* __restrict__ h1, float* __restrict__ a_s, float* __restrict__ a_d) {
    int lane = threadIdx.x & 63;
    int wid = (blockIdx.x * blockDim.x + threadIdx.x) >> 6;
    int nw = (gridDim.x * blockDim.x) >> 6;
    float w[7];
#pragma unroll
    for (int k = 0; k < 7; ++k) w[k] = W1[k * 64 + lane];
    float asl = as1[lane], adl = ad1[lane];
    float xv = (wid < T_ * N_ && lane < 7) ? x[(size_t)wid * 7 + lane] : 0.f;
    for (int r = wid; r < T_ * N_; r += nw) {
        float xcur = xv;
        int rn = r + nw;
        if (rn < T_ * N_ && lane < 7) xv = x[(size_t)rn * 7 + lane];
        float acc = 0.f;
#pragma unroll
        for (int k = 0; k < 7; ++k) acc = fmaf(rdlane(xcur, k), w[k], acc);
        h1[(size_t)r * 64 + lane] = acc;
        float s = acc * asl, d = acc * adl;
#pragma unroll
        for (int m = 1; m < 32; m <<= 1) { s += __shfl_xor(s, m); d += __shfl_xor(d, m); }
        if ((lane & 31) == 0) {
            a_s[r * 2 + (lane >> 5)] = s;
            a_d[r * 2 + (lane >> 5)] = d;
        }
    }
}

// ---- CSR build: range-partitioned degree histogram (LDS, no global atomics) ----
__global__ __launch_bounds__(256) void k_degR(const int* __restrict__ ei,
                                              int* __restrict__ deg) {
    int t = blockIdx.x & 15, rg = blockIdx.x >> 4;
    __shared__ int hist[RNODES];
    for (int i = threadIdx.x; i < RNODES; i += 256) hist[i] = 0;
    __syncthreads();
    int r0 = rg * RNODES, r1 = min(r0 + RNODES, N_);
    const int4* db4 = (const int4*)(ei + (size_t)t * 2 * E_ + E_);
    for (int i = threadIdx.x; i < E_ / 4; i += 256) {
        int4 d = db4[i];
        if (d.x >= r0 && d.x < r1) atomicAdd(&hist[d.x - r0], 1);
        if (d.y >= r0 && d.y < r1) atomicAdd(&hist[d.y - r0], 1);
        if (d.z >= r0 && d.z < r1) atomicAdd(&hist[d.z - r0], 1);
        if (d.w >= r0 && d.w < r1) atomicAdd(&hist[d.w - r0], 1);
    }
    __syncthreads();
    for (int i = threadIdx.x; i < r1 - r0; i += 256) deg[t * N_ + r0 + i] = hist[i];
}

// ---- per-frame exclusive scan of (deg+1); shfl-based; writes rowptr ----
__global__ __launch_bounds__(1024) void k_scan(const int* __restrict__ deg,
                                               int* __restrict__ rowptr) {
    int t = blockIdx.x;
    __shared__ int wsum[16];
    __shared__ int carryS;
    int tid = threadIdx.x, lane = tid & 63, wv = tid >> 6;
    if (tid == 0) { carryS = 0; rowptr[t * (N_ + 1)] = 0; }
    __syncthreads();
    for (int base = 0; base < N_; base += 1024) {
        int i = base + tid;
        int v = (i < N_) ? deg[t * N_ + i] + 1 : 0;
        int s = v;
#pragma unroll
        for (int off = 1; off < 64; off <<= 1) {
            int u = __shfl_up(s, off);
            if (lane >= off) s += u;
        }
        if (lane == 63) wsum[wv] = s;
        __syncthreads();
        if (wv == 0 && lane < 16) {
            int ws = wsum[lane];
            int sc = ws;
#pragma unroll
            for (int off = 1; off < 16; off <<= 1) {
                int u = __shfl_up(sc, off);
                if (lane >= off) sc += u;
            }
            wsum[lane] = sc - ws;
        }
        __syncthreads();
        int incl = s + wsum[wv] + carryS;
        if (i < N_) rowptr[t * (N_ + 1) + i + 1] = incl;
        __syncthreads();
        if (tid == 1023) carryS = incl;
        __syncthreads();
    }
}

// ---- range-partitioned scatter: LDS cursors, single-writer col slices ----
__global__ __launch_bounds__(256) void k_scatR(const int* __restrict__ ei,
                                               const int* __restrict__ rowptr,
                                               int* __restrict__ col) {
    int t = blockIdx.x & 15, rg = blockIdx.x >> 4;
    __shared__ int curL[RNODES];
    int r0 = rg * RNODES, r1 = min(r0 + RNODES, N_);
    const int* rp = rowptr + t * (N_ + 1);
    for (int i = threadIdx.x; i < r1 - r0; i += 256) curL[i] = rp[r0 + i];
    __syncthreads();
    const int4* db4 = (const int4*)(ei + (size_t)t * 2 * E_ + E_);
    const int4* sb4 = (const int4*)(ei + (size_t)t * 2 * E_);
    int* cf = col + (size_t)t * EN_;
    for (int i = threadIdx.x; i < E_ / 4; i += 256) {
        int4 d = db4[i];
        bool ax = d.x >= r0 && d.x < r1, ay = d.y >= r0 && d.y < r1;
        bool az = d.z >= r0 && d.z < r1, aw = d.w >= r0 && d.w < r1;
        if (ax | ay | az | aw) {
            int4 s = sb4[i];
            if (ax) cf[atomicAdd(&curL[d.x - r0], 1)] = s.x;
            if (ay) cf[atomicAdd(&curL[d.y - r0], 1)] = s.y;
            if (az) cf[atomicAdd(&curL[d.z - r0], 1)] = s.z;
            if (aw) cf[atomicAdd(&curL[d.w - r0], 1)] = s.w;
        }
    }
    __syncthreads();
    // self-loop fills the reserved last slot of each node's segment
    for (int i = threadIdx.x; i < r1 - r0; i += 256) cf[curL[i]] = r0 + i;
}

// ---- gather-aggregate: wave per (t,node), frame-affine; exp deduped via readlane ----
template <int HEADS>
__global__ __launch_bounds__(256) void k_agg(
    const int* __restrict__ rowptr, const int* __restrict__ col,
    const float* __restrict__ a_s, const float* __restrict__ a_d,
    const float* __restrict__ hin, const float* __restrict__ bias,
    float* __restrict__ outp) {
    int t, local;
    frame_map(blockIdx.x, &t, &local);
    int lane = threadIdx.x & 63;
    int n = local * 4 + (threadIdx.x >> 6);
    if (n >= N_) return;
    int node = t * N_ + n;
    float ad0 = a_d[node * HEADS];
    float ad1 = (HEADS == 2) ? a_d[node * HEADS + 1] : 0.f;
    int e0 = rowptr[t * (N_ + 1) + n], e1 = rowptr[t * (N_ + 1) + n + 1];
    const int* cb = col + (size_t)t * EN_;
    const float* hb = hin + (size_t)t * N_ * 64;
    const float* ab = a_s + (size_t)t * N_ * HEADS;
    float acc = 0.f, acc2 = 0.f, den0 = 0.f, den1 = 0.f;
    for (int base = e0; base < e1; base += 64) {
        int rem = e1 - base; if (rem > 64) rem = 64;
        int s = 0; float p0 = 0.f, p1 = 0.f;
        if (lane < rem) {
            s = cb[base + lane];
            p0 = expf(lrelu(ab[s * HEADS] + ad0));
            if (HEADS == 2) p1 = expf(lrelu(ab[s * HEADS + 1] + ad1));
        }
        den0 += p0; den1 += p1;
        int k = 0;
        for (; k + 1 < rem; k += 2) {
            int s0 = __builtin_amdgcn_readlane(s, k);
            int s1 = __builtin_amdgcn_readlane(s, k + 1);
            float pk0, pk1;
            if (HEADS == 2) {
                float pa0 = rdlane(p0, k), pa1 = rdlane(p0, k + 1);
                float pb0 = rdlane(p1, k), pb1 = rdlane(p1, k + 1);
                pk0 = (lane < 32) ? pa0 : pb0;
                pk1 = (lane < 32) ? pa1 : pb1;
            } else {
                pk0 = rdlane(p0, k); pk1 = rdlane(p0, k + 1);
            }
            acc  = fmaf(pk0, hb[(size_t)s0 * 64 + lane], acc);
            acc2 = fmaf(pk1, hb[(size_t)s1 * 64 + lane], acc2);
        }
        if (k < rem) {
            int s0 = __builtin_amdgcn_readlane(s, k);
            float pk0 = (HEADS == 2) ? ((lane < 32) ? rdlane(p0, k) : rdlane(p1, k))
                                     : rdlane(p0, k);
            acc = fmaf(pk0, hb[(size_t)s0 * 64 + lane], acc);
        }
    }
    acc += acc2;
#pragma unroll
    for (int m = 1; m < 64; m <<= 1) {
        den0 += __shfl_xor(den0, m);
        if (HEADS == 2) den1 += __shfl_xor(den1, m);
    }
    float den = (HEADS == 2) ? ((lane < 32) ? den0 : den1) : den0;
    outp[(size_t)node * 64 + lane] = elu(acc / (den + 1e-16f) + bias[lane]);
}

// ---- layer 2 GEMM: wave-per-row grid-stride; W2 column in 64 VGPRs ----
__global__ __launch_bounds__(256) void k_h2(
    const float* __restrict__ xin, const float* __restrict__ W2,
    const float* __restrict__ as2, const float* __restrict__ ad2,
    float* __restrict__ h2, float* __restrict__ a_s, float* __restrict__ a_d) {
    int lane = threadIdx.x & 63;
    int wid = (blockIdx.x * blockDim.x + threadIdx.x) >> 6;
    int nw = (gridDim.x * blockDim.x) >> 6;
    float w[64];
#pragma unroll
    for (int k = 0; k < 64; ++k) w[k] = W2[k * 64 + lane];
    float asl = as2[lane], adl = ad2[lane];
    float xv = (wid < T_ * N_) ? xin[(size_t)wid * 64 + lane] : 0.f;
    for (int r = wid; r < T_ * N_; r += nw) {
        float xcur = xv;
        int rn = r + nw;
        if (rn < T_ * N_) xv = xin[(size_t)rn * 64 + lane];
        float acc = 0.f;
#pragma unroll
        for (int k = 0; k < 64; ++k) acc = fmaf(rdlane(xcur, k), w[k], acc);
        h2[(size_t)r * 64 + lane] = acc;
        float s = acc * asl, d = acc * adl;
#pragma unroll
        for (int m = 1; m < 64; m <<= 1) { s += __shfl_xor(s, m); d += __shfl_xor(d, m); }
        if (lane == 0) { a_s[r] = s; a_d[r] = d; }
    }
}

// ---- sorted-batch mean-pool over activated node features ----
__global__ void k_pool(const float* __restrict__ hact, const int* __restrict__ batch,
                       float* __restrict__ sums, float* __restrict__ cnt) {
    int wid = (blockIdx.x * blockDim.x + threadIdx.x) >> 6;
    int lane = threadIdx.x & 63;
    const int WPF = (N_ + 63) / 64;
    int t = wid / WPF, w = wid - t * WPF;
    if (t >= T_) return;
    int n0 = w * 64, n1 = min(n0 + 64, N_);
    float acc = 0.f, cacc = 0.f;
    int cur_b = batch[t * N_ + n0];
    for (int n = n0; n < n1; ++n) {
        int b = batch[t * N_ + n];
        if (b != cur_b) {
            atomicAdd(&sums[(t * B_ + cur_b) * 64 + lane], acc);
            if (lane == 0) atomicAdd(&cnt[t * B_ + cur_b], cacc);
            acc = 0.f; cacc = 0.f; cur_b = b;
        }
        acc += hact[(size_t)(t * N_ + n) * 64 + lane];
        cacc += 1.f;
    }
    atomicAdd(&sums[(t * B_ + cur_b) * 64 + lane], acc);
    if (lane == 0) atomicAdd(&cnt[t * B_ + cur_b], cacc);
}

__global__ void k_emb(const float* __restrict__ sums, const float* __restrict__ cnt,
                      float* __restrict__ emb) {
    int idx = blockIdx.x * blockDim.x + threadIdx.x;
    if (idx >= T_ * B_ * 64) return;
    emb[idx] = sums[idx] / fmaxf(cnt[idx >> 6], 1.0f);
}

__global__ void k_gx(const float* __restrict__ emb, const float* __restrict__ Wih,
                     const float* __restrict__ bih, float* __restrict__ gx) {
    int idx = blockIdx.x * blockDim.x + threadIdx.x;
    if (idx >= T_ * B_ * 192) return;
    int tb = idx / 192, g = idx - tb * 192;
    const float* er = emb + tb * 64;
    const float* wr = Wih + g * 64;
    float acc = bih[g];
#pragma unroll
    for (int k = 0; k < 64; ++k) acc = fmaf(er[k], wr[k], acc);
    gx[idx] = acc;
}

// ---- sequential GRU + classifier head (single block); Wh padded stride 65 ----
__global__ __launch_bounds__(1024) void k_gru(
    const float* __restrict__ gx_all, const float* __restrict__ Whh,
    const float* __restrict__ bhh, const float* __restrict__ Wc1,
    const float* __restrict__ bc1, const float* __restrict__ Wc2,
    const float* __restrict__ bc2, float* __restrict__ out) {
    __shared__ float Wh[192 * 65];
    __shared__ float hL[16 * 64];
    __shared__ float gh[16 * 192];
    __shared__ float hid[16 * 32];
    int tid = threadIdx.x;
    for (int i = tid; i < 192 * 64; i += 1024) Wh[(i >> 6) * 65 + (i & 63)] = Whh[i];
    hL[tid] = 0.f;
    __syncthreads();
    for (int t = 0; t < T_; ++t) {
        for (int idx = tid; idx < 16 * 192; idx += 1024) {
            int b = idx / 192, g = idx - b * 192;
            float acc = bhh[g];
            const float* wr = Wh + g * 65;
            const float* hr = hL + b * 64;
#pragma unroll
            for (int k = 0; k < 64; ++k) acc = fmaf(hr[k], wr[k], acc);
            gh[idx] = acc;
        }
        __syncthreads();
        const float* gxt = gx_all + t * 16 * 192;
        {
            int b = tid >> 6, c = tid & 63;
            float xr = gxt[b * 192 + c], xz = gxt[b * 192 + 64 + c], xn = gxt[b * 192 + 128 + c];
            float hr_ = gh[b * 192 + c], hz = gh[b * 192 + 64 + c], hn = gh[b * 192 + 128 + c];
            float r = 1.f / (1.f + expf(-(xr + hr_)));
            float z = 1.f / (1.f + expf(-(xz + hz)));
            float n = tanhf(xn + r * hn);
            hL[tid] = (1.f - z) * n + z * hL[tid];
        }
        __syncthreads();
    }
    for (int idx = tid; idx < 16 * 32; idx += 1024) {
        int b = idx >> 5, j = idx & 31;
        float acc = bc1[j];
#pragma unroll
        for (int k = 0; k < 64; ++k) acc = fmaf(hL[b * 64 + k], Wc1[k * 32 + j], acc);
        hid[idx] = fmaxf(acc, 0.f);
    }
    __syncthreads();
    if (tid < 16) {
        float acc = bc2[0];
#pragma unroll
        for (int k = 0; k < 32; ++k) acc = fmaf(hid[tid * 32 + k], Wc2[k], acc);
        out[tid] = acc;
    }
}

extern "C" void kernel_launch(void* const* d_in, const int* in_sizes, int n_in,
                              void* d_out, int out_size, void* d_ws, size_t ws_size,
                              hipStream_t stream) {
    const float* x   = (const float*)d_in[0];
    const int*   ei  = (const int*)d_in[1];
    const int* batch = (const int*)d_in[2];
    const float* W1  = (const float*)d_in[3];
    const float* as1 = (const float*)d_in[4];
    const float* ad1 = (const float*)d_in[5];
    const float* b1  = (const float*)d_in[6];
    const float* W2  = (const float*)d_in[7];
    const float* as2 = (const float*)d_in[8];
    const float* ad2 = (const float*)d_in[9];
    const float* b2  = (const float*)d_in[10];
    const float* Wih = (const float*)d_in[11];
    const float* Whh = (const float*)d_in[12];
    const float* bih = (const float*)d_in[13];
    const float* bhh = (const float*)d_in[14];
    const float* Wc1 = (const float*)d_in[15];
    const float* bc1 = (const float*)d_in[16];
    const float* Wc2 = (const float*)d_in[17];
    const float* bc2 = (const float*)d_in[18];
    float* out = (float*)d_out;

    float* ws = (float*)d_ws;
    float* hA     = ws;                      // 20,480,000 (h1 / h2)
    float* hX     = hA + 20480000;           // 20,480,000 (activated xin / out2)
    float* a_s    = hX + 20480000;           // 640,000
    float* a_d    = a_s + 640000;            // 640,000
    int*   rowptr = (int*)(a_d + 640000);    // 16*(N+1) -> pad 320,032
    int*   deg    = rowptr + 320032;         // 320,000
    int*   col    = deg + 320000;            // 16*EN = 5,440,000
    float* sums   = (float*)(col + 5440000); // 16,384
    float* cnt    = sums + 16384;            // 256
    float* emb    = cnt + 256;               // 16,384
    float* gx     = emb + 16384;             // 49,152

    const int BPF_AGG = (N_ + 3) / 4;        // 5000 (4 nodes/block)

    hipMemsetAsync(sums, 0, (size_t)(16384 + 256) * 4, stream);

    // ---- CSR build (range-partitioned, no global atomics) ----
    k_degR<<<16 * RPF, 256, 0, stream>>>(ei, deg);
    k_scan<<<T_, 1024, 0, stream>>>(deg, rowptr);
    k_scatR<<<16 * RPF, 256, 0, stream>>>(ei, rowptr, col);

    // ---- layer 1 ----
    k_h1<<<1024, 256, 0, stream>>>(x, W1, as1, ad1, hA, a_s, a_d);
    k_agg<2><<<16 * BPF_AGG, 256, 0, stream>>>(rowptr, col, a_s, a_d, hA, b1, hX);

    // ---- layer 2 ----
    k_h2<<<1024, 256, 0, stream>>>(hX, W2, as2, ad2, hA, a_s, a_d);
    k_agg<1><<<16 * BPF_AGG, 256, 0, stream>>>(rowptr, col, a_s, a_d, hA, b2, hX);

    // ---- pool + GRU + head ----
    {
        const int WPF = (N_ + 63) / 64;
        int waves = T_ * WPF;
        k_pool<<<(waves * 64 + 255) / 256, 256, 0, stream>>>(hX, batch, sums, cnt);
    }
    k_emb<<<(T_ * B_ * 64 + 255) / 256, 256, 0, stream>>>(sums, cnt, emb);
    k_gx<<<(T_ * B_ * 192 + 255) / 256, 256, 0, stream>>>(emb, Wih, bih, gx);
    k_gru<<<1, 1024, 0, stream>>>(gx, Whh, bhh, Wc1, bc1, Wc2, bc2, out);
}

// Round 8
// 1172.684 us; speedup vs baseline: 1.1586x; 1.1586x over previous
//
#include <hip/hip_runtime.h>
#include <math.h>

#define T_ 16
#define N_ 20000
#define E_ 320000
#define EN_ (E_ + N_)
#define B_ 16
#define RPF 32
#define RNODES (N_ / RPF)        // 625 nodes per range (exact)
#define SLICE_CAP 12544          // expected 10625, sigma~100 -> +19 sigma headroom
#define DEGB 8                   // partial-histogram blocks per frame

__device__ __forceinline__ float lrelu(float v) { return v >= 0.f ? v : 0.2f * v; }
__device__ __forceinline__ float elu(float v) { return v > 0.f ? v : expm1f(v); }
__device__ __forceinline__ float rdlane(float v, int k) {
    return __uint_as_float(__builtin_amdgcn_readlane(__float_as_uint(v), k));
}

__device__ __forceinline__ void frame_map(int bid, int* frame, int* local) {
    int blk = bid >> 3;
    *frame = (bid & 7) * 2 + (blk & 1);
    *local = blk >> 1;
}

// ---- layer 1: h1 = x @ W1 (7->64), per-head attention dots ----
__global__ __launch_bounds__(256) void k_h1(
    const float* __restrict__ x, const float* __restrict__ W1,
    const float* __restrict__ as1, const float* __restrict__ ad1,
    float* __restrict__ h1, float* __restrict__ a_s, float* __restrict__ a_d) {
    int lane = threadIdx.x & 63;
    int wid = (blockIdx.x * blockDim.x + threadIdx.x) >> 6;
    int nw = (gridDim.x * blockDim.x) >> 6;
    float w[7];
#pragma unroll
    for (int k = 0; k < 7; ++k) w[k] = W1[k * 64 + lane];
    float asl = as1[lane], adl = ad1[lane];
    float xv = (wid < T_ * N_ && lane < 7) ? x[(size_t)wid * 7 + lane] : 0.f;
    for (int r = wid; r < T_ * N_; r += nw) {
        float xcur = xv;
        int rn = r + nw;
        if (rn < T_ * N_ && lane < 7) xv = x[(size_t)rn * 7 + lane];
        float acc = 0.f;
#pragma unroll
        for (int k = 0; k < 7; ++k) acc = fmaf(rdlane(xcur, k), w[k], acc);
        h1[(size_t)r * 64 + lane] = acc;
        float s = acc * asl, d = acc * adl;
#pragma unroll
        for (int m = 1; m < 32; m <<= 1) { s += __shfl_xor(s, m); d += __shfl_xor(d, m); }
        if ((lane & 31) == 0) {
            a_s[r * 2 + (lane >> 5)] = s;
            a_d[r * 2 + (lane >> 5)] = d;
        }
    }
}

// ---- CSR build: full-frame LDS histogram, DEGB partial blocks per frame ----
__global__ __launch_bounds__(256) void k_degF(const int* __restrict__ ei,
                                              int* __restrict__ deg) {
    int t = blockIdx.x & 15, part = blockIdx.x >> 4;   // part in [0,DEGB)
    __shared__ int hist[N_];                            // 80 KB
    for (int i = threadIdx.x; i < N_; i += 256) hist[i] = 0;
    __syncthreads();
    const int4* db4 = (const int4*)(ei + (size_t)t * 2 * E_ + E_);
    const int per = E_ / 4 / DEGB;                      // 10000 int4 per part
    int i0 = part * per, i1 = i0 + per;
    for (int i = i0 + threadIdx.x; i < i1; i += 256) {
        int4 d = db4[i];
        atomicAdd(&hist[d.x], 1);
        atomicAdd(&hist[d.y], 1);
        atomicAdd(&hist[d.z], 1);
        atomicAdd(&hist[d.w], 1);
    }
    __syncthreads();
    for (int i = threadIdx.x; i < N_; i += 256) {
        int v = hist[i];
        if (v) atomicAdd(&deg[t * N_ + i], v);
    }
}

// ---- per-frame exclusive scan of (deg+1); shfl-based; writes rowptr ----
__global__ __launch_bounds__(1024) void k_scan(const int* __restrict__ deg,
                                               int* __restrict__ rowptr) {
    int t = blockIdx.x;
    __shared__ int wsum[16];
    __shared__ int carryS;
    int tid = threadIdx.x, lane = tid & 63, wv = tid >> 6;
    if (tid == 0) { carryS = 0; rowptr[t * (N_ + 1)] = 0; }
    __syncthreads();
    for (int base = 0; base < N_; base += 1024) {
        int i = base + tid;
        int v = (i < N_) ? deg[t * N_ + i] + 1 : 0;
        int s = v;
#pragma unroll
        for (int off = 1; off < 64; off <<= 1) {
            int u = __shfl_up(s, off);
            if (lane >= off) s += u;
        }
        if (lane == 63) wsum[wv] = s;
        __syncthreads();
        if (wv == 0 && lane < 16) {
            int ws = wsum[lane];
            int sc = ws;
#pragma unroll
            for (int off = 1; off < 16; off <<= 1) {
                int u = __shfl_up(sc, off);
                if (lane >= off) sc += u;
            }
            wsum[lane] = sc - ws;
        }
        __syncthreads();
        int incl = s + wsum[wv] + carryS;
        if (i < N_) rowptr[t * (N_ + 1) + i + 1] = incl;
        __syncthreads();
        if (tid == 1023) carryS = incl;
        __syncthreads();
    }
}

// ---- range-partitioned scatter with LDS slice staging -> dense flush ----
__global__ __launch_bounds__(256) void k_scatR(const int* __restrict__ ei,
                                               const int* __restrict__ rowptr,
                                               int* __restrict__ col) {
    int t = blockIdx.x & 15, rg = blockIdx.x >> 4;
    __shared__ int curL[RNODES];        // absolute cursor positions
    __shared__ int colL[SLICE_CAP];     // staged slice
    int r0 = rg * RNODES;
    const int* rp = rowptr + t * (N_ + 1);
    int sliceBase = rp[r0];
    int sliceLen = rp[r0 + RNODES] - sliceBase;
    bool ovf = sliceLen > SLICE_CAP;    // safety net; never taken for random graphs
    for (int i = threadIdx.x; i < RNODES; i += 256) curL[i] = rp[r0 + i];
    __syncthreads();
    const int4* db4 = (const int4*)(ei + (size_t)t * 2 * E_ + E_);
    const int4* sb4 = (const int4*)(ei + (size_t)t * 2 * E_);
    int* cf = col + (size_t)t * EN_;
    for (int i = threadIdx.x; i < E_ / 4; i += 256) {
        int4 d = db4[i];
        bool ax = (unsigned)(d.x - r0) < (unsigned)RNODES;
        bool ay = (unsigned)(d.y - r0) < (unsigned)RNODES;
        bool az = (unsigned)(d.z - r0) < (unsigned)RNODES;
        bool aw = (unsigned)(d.w - r0) < (unsigned)RNODES;
        if (ax | ay | az | aw) {
            int4 s = sb4[i];
            if (ax) { int p = atomicAdd(&curL[d.x - r0], 1);
                      if (ovf) cf[p] = s.x; else colL[p - sliceBase] = s.x; }
            if (ay) { int p = atomicAdd(&curL[d.y - r0], 1);
                      if (ovf) cf[p] = s.y; else colL[p - sliceBase] = s.y; }
            if (az) { int p = atomicAdd(&curL[d.z - r0], 1);
                      if (ovf) cf[p] = s.z; else colL[p - sliceBase] = s.z; }
            if (aw) { int p = atomicAdd(&curL[d.w - r0], 1);
                      if (ovf) cf[p] = s.w; else colL[p - sliceBase] = s.w; }
        }
    }
    __syncthreads();
    // self-loop fills the reserved last slot of each node's segment
    for (int i = threadIdx.x; i < RNODES; i += 256) {
        int p = curL[i];
        if (ovf) cf[p] = r0 + i; else colL[p - sliceBase] = r0 + i;
    }
    __syncthreads();
    if (!ovf)
        for (int i = threadIdx.x; i < sliceLen; i += 256) cf[sliceBase + i] = colL[i];
}

// ---- gather-aggregate: wave per (t,node), frame-affine; exp deduped via readlane ----
template <int HEADS>
__global__ __launch_bounds__(256) void k_agg(
    const int* __restrict__ rowptr, const int* __restrict__ col,
    const float* __restrict__ a_s, const float* __restrict__ a_d,
    const float* __restrict__ hin, const float* __restrict__ bias,
    float* __restrict__ outp) {
    int t, local;
    frame_map(blockIdx.x, &t, &local);
    int lane = threadIdx.x & 63;
    int n = local * 4 + (threadIdx.x >> 6);
    if (n >= N_) return;
    int node = t * N_ + n;
    float ad0 = a_d[node * HEADS];
    float ad1 = (HEADS == 2) ? a_d[node * HEADS + 1] : 0.f;
    int e0 = rowptr[t * (N_ + 1) + n], e1 = rowptr[t * (N_ + 1) + n + 1];
    const int* cb = col + (size_t)t * EN_;
    const float* hb = hin + (size_t)t * N_ * 64;
    const float* ab = a_s + (size_t)t * N_ * HEADS;
    float acc = 0.f, acc2 = 0.f, den0 = 0.f, den1 = 0.f;
    for (int base = e0; base < e1; base += 64) {
        int rem = e1 - base; if (rem > 64) rem = 64;
        int s = 0; float p0 = 0.f, p1 = 0.f;
        if (lane < rem) {
            s = cb[base + lane];
            p0 = expf(lrelu(ab[s * HEADS] + ad0));
            if (HEADS == 2) p1 = expf(lrelu(ab[s * HEADS + 1] + ad1));
        }
        den0 += p0; den1 += p1;
        int k = 0;
        for (; k + 1 < rem; k += 2) {
            int s0 = __builtin_amdgcn_readlane(s, k);
            int s1 = __builtin_amdgcn_readlane(s, k + 1);
            float pk0, pk1;
            if (HEADS == 2) {
                float pa0 = rdlane(p0, k), pa1 = rdlane(p0, k + 1);
                float pb0 = rdlane(p1, k), pb1 = rdlane(p1, k + 1);
                pk0 = (lane < 32) ? pa0 : pb0;
                pk1 = (lane < 32) ? pa1 : pb1;
            } else {
                pk0 = rdlane(p0, k); pk1 = rdlane(p0, k + 1);
            }
            acc  = fmaf(pk0, hb[(size_t)s0 * 64 + lane], acc);
            acc2 = fmaf(pk1, hb[(size_t)s1 * 64 + lane], acc2);
        }
        if (k < rem) {
            int s0 = __builtin_amdgcn_readlane(s, k);
            float pk0 = (HEADS == 2) ? ((lane < 32) ? rdlane(p0, k) : rdlane(p1, k))
                                     : rdlane(p0, k);
            acc = fmaf(pk0, hb[(size_t)s0 * 64 + lane], acc);
        }
    }
    acc += acc2;
#pragma unroll
    for (int m = 1; m < 64; m <<= 1) {
        den0 += __shfl_xor(den0, m);
        if (HEADS == 2) den1 += __shfl_xor(den1, m);
    }
    float den = (HEADS == 2) ? ((lane < 32) ? den0 : den1) : den0;
    outp[(size_t)node * 64 + lane] = elu(acc / (den + 1e-16f) + bias[lane]);
}

// ---- layer 2 GEMM: wave-per-row grid-stride; W2 column in 64 VGPRs ----
__global__ __launch_bounds__(256) void k_h2(
    const float* __restrict__ xin, const float* __restrict__ W2,
    const float* __restrict__ as2, const float* __restrict__ ad2,
    float* __restrict__ h2, float* __restrict__ a_s, float* __restrict__ a_d) {
    int lane = threadIdx.x & 63;
    int wid = (blockIdx.x * blockDim.x + threadIdx.x) >> 6;
    int nw = (gridDim.x * blockDim.x) >> 6;
    float w[64];
#pragma unroll
    for (int k = 0; k < 64; ++k) w[k] = W2[k * 64 + lane];
    float asl = as2[lane], adl = ad2[lane];
    float xv = (wid < T_ * N_) ? xin[(size_t)wid * 64 + lane] : 0.f;
    for (int r = wid; r < T_ * N_; r += nw) {
        float xcur = xv;
        int rn = r + nw;
        if (rn < T_ * N_) xv = xin[(size_t)rn * 64 + lane];
        float acc = 0.f;
#pragma unroll
        for (int k = 0; k < 64; ++k) acc = fmaf(rdlane(xcur, k), w[k], acc);
        h2[(size_t)r * 64 + lane] = acc;
        float s = acc * asl, d = acc * adl;
#pragma unroll
        for (int m = 1; m < 64; m <<= 1) { s += __shfl_xor(s, m); d += __shfl_xor(d, m); }
        if (lane == 0) { a_s[r] = s; a_d[r] = d; }
    }
}

// ---- sorted-batch mean-pool over activated node features ----
__global__ void k_pool(const float* __restrict__ hact, const int* __restrict__ batch,
                       float* __restrict__ sums, float* __restrict__ cnt) {
    int wid = (blockIdx.x * blockDim.x + threadIdx.x) >> 6;
    int lane = threadIdx.x & 63;
    const int WPF = (N_ + 63) / 64;
    int t = wid / WPF, w = wid - t * WPF;
    if (t >= T_) return;
    int n0 = w * 64, n1 = min(n0 + 64, N_);
    float acc = 0.f, cacc = 0.f;
    int cur_b = batch[t * N_ + n0];
    for (int n = n0; n < n1; ++n) {
        int b = batch[t * N_ + n];
        if (b != cur_b) {
            atomicAdd(&sums[(t * B_ + cur_b) * 64 + lane], acc);
            if (lane == 0) atomicAdd(&cnt[t * B_ + cur_b], cacc);
            acc = 0.f; cacc = 0.f; cur_b = b;
        }
        acc += hact[(size_t)(t * N_ + n) * 64 + lane];
        cacc += 1.f;
    }
    atomicAdd(&sums[(t * B_ + cur_b) * 64 + lane], acc);
    if (lane == 0) atomicAdd(&cnt[t * B_ + cur_b], cacc);
}

__global__ void k_emb(const float* __restrict__ sums, const float* __restrict__ cnt,
                      float* __restrict__ emb) {
    int idx = blockIdx.x * blockDim.x + threadIdx.x;
    if (idx >= T_ * B_ * 64) return;
    emb[idx] = sums[idx] / fmaxf(cnt[idx >> 6], 1.0f);
}

__global__ void k_gx(const float* __restrict__ emb, const float* __restrict__ Wih,
                     const float* __restrict__ bih, float* __restrict__ gx) {
    int idx = blockIdx.x * blockDim.x + threadIdx.x;
    if (idx >= T_ * B_ * 192) return;
    int tb = idx / 192, g = idx - tb * 192;
    const float* er = emb + tb * 64;
    const float* wr = Wih + g * 64;
    float acc = bih[g];
#pragma unroll
    for (int k = 0; k < 64; ++k) acc = fmaf(er[k], wr[k], acc);
    gx[idx] = acc;
}

// ---- sequential GRU + classifier head (single block); Wh padded stride 65 ----
__global__ __launch_bounds__(1024) void k_gru(
    const float* __restrict__ gx_all, const float* __restrict__ Whh,
    const float* __restrict__ bhh, const float* __restrict__ Wc1,
    const float* __restrict__ bc1, const float* __restrict__ Wc2,
    const float* __restrict__ bc2, float* __restrict__ out) {
    __shared__ float Wh[192 * 65];
    __shared__ float hL[16 * 64];
    __shared__ float gh[16 * 192];
    __shared__ float hid[16 * 32];
    int tid = threadIdx.x;
    for (int i = tid; i < 192 * 64; i += 1024) Wh[(i >> 6) * 65 + (i & 63)] = Whh[i];
    hL[tid] = 0.f;
    __syncthreads();
    for (int t = 0; t < T_; ++t) {
        for (int idx = tid; idx < 16 * 192; idx += 1024) {
            int b = idx / 192, g = idx - b * 192;
            float acc = bhh[g];
            const float* wr = Wh + g * 65;
            const float* hr = hL + b * 64;
#pragma unroll
            for (int k = 0; k < 64; ++k) acc = fmaf(hr[k], wr[k], acc);
            gh[idx] = acc;
        }
        __syncthreads();
        const float* gxt = gx_all + t * 16 * 192;
        {
            int b = tid >> 6, c = tid & 63;
            float xr = gxt[b * 192 + c], xz = gxt[b * 192 + 64 + c], xn = gxt[b * 192 + 128 + c];
            float hr_ = gh[b * 192 + c], hz = gh[b * 192 + 64 + c], hn = gh[b * 192 + 128 + c];
            float r = 1.f / (1.f + expf(-(xr + hr_)));
            float z = 1.f / (1.f + expf(-(xz + hz)));
            float n = tanhf(xn + r * hn);
            hL[tid] = (1.f - z) * n + z * hL[tid];
        }
        __syncthreads();
    }
    for (int idx = tid; idx < 16 * 32; idx += 1024) {
        int b = idx >> 5, j = idx & 31;
        float acc = bc1[j];
#pragma unroll
        for (int k = 0; k < 64; ++k) acc = fmaf(hL[b * 64 + k], Wc1[k * 32 + j], acc);
        hid[idx] = fmaxf(acc, 0.f);
    }
    __syncthreads();
    if (tid < 16) {
        float acc = bc2[0];
#pragma unroll
        for (int k = 0; k < 32; ++k) acc = fmaf(hid[tid * 32 + k], Wc2[k], acc);
        out[tid] = acc;
    }
}

extern "C" void kernel_launch(void* const* d_in, const int* in_sizes, int n_in,
                              void* d_out, int out_size, void* d_ws, size_t ws_size,
                              hipStream_t stream) {
    const float* x   = (const float*)d_in[0];
    const int*   ei  = (const int*)d_in[1];
    const int* batch = (const int*)d_in[2];
    const float* W1  = (const float*)d_in[3];
    const float* as1 = (const float*)d_in[4];
    const float* ad1 = (const float*)d_in[5];
    const float* b1  = (const float*)d_in[6];
    const float* W2  = (const float*)d_in[7];
    const float* as2 = (const float*)d_in[8];
    const float* ad2 = (const float*)d_in[9];
    const float* b2  = (const float*)d_in[10];
    const float* Wih = (const float*)d_in[11];
    const float* Whh = (const float*)d_in[12];
    const float* bih = (const float*)d_in[13];
    const float* bhh = (const float*)d_in[14];
    const float* Wc1 = (const float*)d_in[15];
    const float* bc1 = (const float*)d_in[16];
    const float* Wc2 = (const float*)d_in[17];
    const float* bc2 = (const float*)d_in[18];
    float* out = (float*)d_out;

    float* ws = (float*)d_ws;
    float* hA     = ws;                      // 20,480,000 (h1 / h2)
    float* hX     = hA + 20480000;           // 20,480,000 (activated xin / out2)
    float* a_s    = hX + 20480000;           // 640,000
    float* a_d    = a_s + 640000;            // 640,000
    int*   rowptr = (int*)(a_d + 640000);    // 16*(N+1) -> pad 320,032
    int*   deg    = rowptr + 320032;         // 320,000
    int*   col    = deg + 320000;            // 16*EN = 5,440,000
    float* sums   = (float*)(col + 5440000); // 16,384
    float* cnt    = sums + 16384;            // 256
    float* emb    = cnt + 256;               // 16,384
    float* gx     = emb + 16384;             // 49,152

    const int BPF_AGG = (N_ + 3) / 4;        // 5000 (4 nodes/block)

    hipMemsetAsync(deg, 0, (size_t)320000 * 4, stream);
    hipMemsetAsync(sums, 0, (size_t)(16384 + 256) * 4, stream);

    // ---- CSR build (LDS-staged, dense writes) ----
    k_degF<<<16 * DEGB, 256, 0, stream>>>(ei, deg);
    k_scan<<<T_, 1024, 0, stream>>>(deg, rowptr);
    k_scatR<<<16 * RPF, 256, 0, stream>>>(ei, rowptr, col);

    // ---- layer 1 ----
    k_h1<<<1024, 256, 0, stream>>>(x, W1, as1, ad1, hA, a_s, a_d);
    k_agg<2><<<16 * BPF_AGG, 256, 0, stream>>>(rowptr, col, a_s, a_d, hA, b1, hX);

    // ---- layer 2 ----
    k_h2<<<1024, 256, 0, stream>>>(hX, W2, as2, ad2, hA, a_s, a_d);
    k_agg<1><<<16 * BPF_AGG, 256, 0, stream>>>(rowptr, col, a_s, a_d, hA, b2, hX);

    // ---- pool + GRU + head ----
    {
        const int WPF = (N_ + 63) / 64;
        int waves = T_ * WPF;
        k_pool<<<(waves * 64 + 255) / 256, 256, 0, stream>>>(hX, batch, sums, cnt);
    }
    k_emb<<<(T_ * B_ * 64 + 255) / 256, 256, 0, stream>>>(sums, cnt, emb);
    k_gx<<<(T_ * B_ * 192 + 255) / 256, 256, 0, stream>>>(emb, Wih, bih, gx);
    k_gru<<<1, 1024, 0, stream>>>(gx, Whh, bhh, Wc1, bc1, Wc2, bc2, out);
}

// Round 9
// 966.304 us; speedup vs baseline: 1.4060x; 1.2136x over previous
//
#include <hip/hip_runtime.h>
#include <math.h>

#define T_ 16
#define N_ 20000
#define E_ 320000
#define EN_ (E_ + N_)
#define B_ 16
#define RPF 32
#define RNODES (N_ / RPF)        // 625 nodes per range (exact)
#define SLICE_CAP 12544          // mean 10625, sigma~100 -> +19 sigma headroom
#define CPB 8                    // chunks per frame for partition passes
#define CHUNK4 (E_ / 4 / CPB)    // 10000 int4 per chunk

__device__ __forceinline__ float lrelu(float v) { return v >= 0.f ? v : 0.2f * v; }
__device__ __forceinline__ float elu(float v) { return v > 0.f ? v : expm1f(v); }
__device__ __forceinline__ float rdlane(float v, int k) {
    return __uint_as_float(__builtin_amdgcn_readlane(__float_as_uint(v), k));
}

__device__ __forceinline__ void frame_map(int bid, int* frame, int* local) {
    int blk = bid >> 3;
    *frame = (bid & 7) * 2 + (blk & 1);
    *local = blk >> 1;
}

// ---- layer 1: h1 = x @ W1 (7->64), per-head attention dots ----
__global__ __launch_bounds__(256) void k_h1(
    const float* __restrict__ x, const float* __restrict__ W1,
    const float* __restrict__ as1, const float* __restrict__ ad1,
    float* __restrict__ h1, float* __restrict__ a_s, float* __restrict__ a_d) {
    int lane = threadIdx.x & 63;
    int wid = (blockIdx.x * blockDim.x + threadIdx.x) >> 6;
    int nw = (gridDim.x * blockDim.x) >> 6;
    float w[7];
#pragma unroll
    for (int k = 0; k < 7; ++k) w[k] = W1[k * 64 + lane];
    float asl = as1[lane], adl = ad1[lane];
    float xv = (wid < T_ * N_ && lane < 7) ? x[(size_t)wid * 7 + lane] : 0.f;
    for (int r = wid; r < T_ * N_; r += nw) {
        float xcur = xv;
        int rn = r + nw;
        if (rn < T_ * N_ && lane < 7) xv = x[(size_t)rn * 7 + lane];
        float acc = 0.f;
#pragma unroll
        for (int k = 0; k < 7; ++k) acc = fmaf(rdlane(xcur, k), w[k], acc);
        h1[(size_t)r * 64 + lane] = acc;
        float s = acc * asl, d = acc * adl;
#pragma unroll
        for (int m = 1; m < 32; m <<= 1) { s += __shfl_xor(s, m); d += __shfl_xor(d, m); }
        if ((lane & 31) == 0) {
            a_s[r * 2 + (lane >> 5)] = s;
            a_d[r * 2 + (lane >> 5)] = d;
        }
    }
}

// ---- partition pass 1: per-(frame,chunk) bucket counts ----
__global__ __launch_bounds__(256) void k_bcnt(const int* __restrict__ ei,
                                              int* __restrict__ blkCnt) {
    int t = blockIdx.x & 15, c = blockIdx.x >> 4;
    __shared__ int cl[RPF];
    if (threadIdx.x < RPF) cl[threadIdx.x] = 0;
    __syncthreads();
    const int4* db4 = (const int4*)(ei + (size_t)t * 2 * E_ + E_) + c * CHUNK4;
    for (int i = threadIdx.x; i < CHUNK4; i += 256) {
        int4 d = db4[i];
        atomicAdd(&cl[d.x / RNODES], 1);
        atomicAdd(&cl[d.y / RNODES], 1);
        atomicAdd(&cl[d.z / RNODES], 1);
        atomicAdd(&cl[d.w / RNODES], 1);
    }
    __syncthreads();
    if (threadIdx.x < RPF)
        blkCnt[(t * CPB + c) * RPF + threadIdx.x] = cl[threadIdx.x];
}

// ---- partition pass 2: scan bucket totals -> bbase[513] and per-block offsets ----
__global__ __launch_bounds__(256) void k_bscan(const int* __restrict__ blkCnt,
                                               int* __restrict__ bbase,
                                               int* __restrict__ blkOff) {
    __shared__ int a0[512], a1[512];
    int tid = threadIdx.x;
    for (int b = tid; b < 512; b += 256) {
        int t = b >> 5, rg = b & 31, s = 0;
        for (int c = 0; c < CPB; ++c) s += blkCnt[((t * CPB + c) << 5) + rg];
        a0[b] = s;
    }
    __syncthreads();
    int* src = a0; int* dst = a1;
    for (int off = 1; off < 512; off <<= 1) {
        for (int i = tid; i < 512; i += 256)
            dst[i] = src[i] + ((i >= off) ? src[i - off] : 0);
        __syncthreads();
        int* tmp = src; src = dst; dst = tmp;
    }
    // src holds inclusive scan
    if (tid == 0) bbase[0] = 0;
    for (int i = tid; i < 512; i += 256) bbase[i + 1] = src[i];
    __syncthreads();
    for (int b = tid; b < 512; b += 256) {
        int t = b >> 5, rg = b & 31;
        int run = bbase[b];
        for (int c = 0; c < CPB; ++c) {
            blkOff[((t * CPB + c) << 5) + rg] = run;
            run += blkCnt[((t * CPB + c) << 5) + rg];
        }
    }
}

// ---- partition pass 3: scatter packed (dstLocal<<15|src) into bucket runs ----
__global__ __launch_bounds__(256) void k_bfill(const int* __restrict__ ei,
                                               const int* __restrict__ blkOff,
                                               int* __restrict__ bucket) {
    int t = blockIdx.x & 15, c = blockIdx.x >> 4;
    __shared__ int curL[RPF];
    if (threadIdx.x < RPF)
        curL[threadIdx.x] = blkOff[(t * CPB + c) * RPF + threadIdx.x];
    __syncthreads();
    const int4* db4 = (const int4*)(ei + (size_t)t * 2 * E_ + E_) + c * CHUNK4;
    const int4* sb4 = (const int4*)(ei + (size_t)t * 2 * E_) + c * CHUNK4;
    for (int i = threadIdx.x; i < CHUNK4; i += 256) {
        int4 d = db4[i];
        int4 s = sb4[i];
        int b, dl, p;
        b = d.x / RNODES; dl = d.x - b * RNODES;
        p = atomicAdd(&curL[b], 1); bucket[p] = (dl << 15) | s.x;
        b = d.y / RNODES; dl = d.y - b * RNODES;
        p = atomicAdd(&curL[b], 1); bucket[p] = (dl << 15) | s.y;
        b = d.z / RNODES; dl = d.z - b * RNODES;
        p = atomicAdd(&curL[b], 1); bucket[p] = (dl << 15) | s.z;
        b = d.w / RNODES; dl = d.w - b * RNODES;
        p = atomicAdd(&curL[b], 1); bucket[p] = (dl << 15) | s.w;
    }
}

// ---- partition pass 4: per-(frame,range) build rowptr span + col slice ----
__global__ __launch_bounds__(256) void k_scat2(const int* __restrict__ bucket,
                                               const int* __restrict__ bbase,
                                               int* __restrict__ rowptr,
                                               int* __restrict__ col) {
    int t = blockIdx.x & 15, rg = blockIdx.x >> 4;
    __shared__ int hist[RNODES];
    __shared__ int cur[RNODES];
    __shared__ int colL[SLICE_CAP];
    __shared__ int wsum[4];
    __shared__ int carryS;
    int tid = threadIdx.x, lane = tid & 63, wv = tid >> 6;
    int bb = bbase[t * RPF + rg];
    int cnt = bbase[t * RPF + rg + 1] - bb;
    int sliceBase = (bb - bbase[t * RPF]) + rg * RNODES;
    int r0 = rg * RNODES;
    bool ovf = (cnt + RNODES) > SLICE_CAP;
    int* rp = rowptr + t * (N_ + 1);
    int* cf = col + (size_t)t * EN_;
    for (int i = tid; i < RNODES; i += 256) hist[i] = 0;
    if (tid == 0) carryS = 0;
    __syncthreads();
    for (int i = tid; i < cnt; i += 256) atomicAdd(&hist[bucket[bb + i] >> 15], 1);
    __syncthreads();
    // inclusive scan of (hist[i]+1) -> cur; rowptr span write
    for (int base = 0; base < RNODES; base += 256) {
        int i = base + tid;
        int v = (i < RNODES) ? hist[i] + 1 : 0;
        int s = v;
#pragma unroll
        for (int off = 1; off < 64; off <<= 1) {
            int u = __shfl_up(s, off);
            if (lane >= off) s += u;
        }
        if (lane == 63) wsum[wv] = s;
        __syncthreads();
        if (tid == 0) {
            int a = 0;
#pragma unroll
            for (int w2 = 0; w2 < 4; ++w2) { int x2 = wsum[w2]; wsum[w2] = a; a += x2; }
        }
        __syncthreads();
        int incl = s + wsum[wv] + carryS;
        if (i < RNODES) {
            cur[i] = incl - v;                    // exclusive base within slice
            rp[r0 + i + 1] = sliceBase + incl;
        }
        __syncthreads();
        if (tid == 255) carryS = incl;
        __syncthreads();
    }
    if (rg == 0 && tid == 0) rp[0] = 0;
    __syncthreads();
    // scatter edges
    for (int i = tid; i < cnt; i += 256) {
        int e = bucket[bb + i];
        int dl = e >> 15, src = e & 0x7FFF;
        int p = atomicAdd(&cur[dl], 1);
        if (ovf) cf[sliceBase + p] = src; else colL[p] = src;
    }
    __syncthreads();
    // self-loop in last slot of each node's segment
    for (int i = tid; i < RNODES; i += 256) {
        int p = cur[i];
        if (ovf) cf[sliceBase + p] = r0 + i; else colL[p] = r0 + i;
    }
    __syncthreads();
    if (!ovf) {
        int len = cnt + RNODES;
        for (int i = tid; i < len; i += 256) cf[sliceBase + i] = colL[i];
    }
}

// ---- gather-aggregate: wave per (t,node), frame-affine; exp deduped via readlane ----
template <int HEADS>
__global__ __launch_bounds__(256) void k_agg(
    const int* __restrict__ rowptr, const int* __restrict__ col,
    const float* __restrict__ a_s, const float* __restrict__ a_d,
    const float* __restrict__ hin, const float* __restrict__ bias,
    float* __restrict__ outp) {
    int t, local;
    frame_map(blockIdx.x, &t, &local);
    int lane = threadIdx.x & 63;
    int n = local * 4 + (threadIdx.x >> 6);
    if (n >= N_) return;
    int node = t * N_ + n;
    float ad0 = a_d[node * HEADS];
    float ad1 = (HEADS == 2) ? a_d[node * HEADS + 1] : 0.f;
    int e0 = rowptr[t * (N_ + 1) + n], e1 = rowptr[t * (N_ + 1) + n + 1];
    const int* cb = col + (size_t)t * EN_;
    const float* hb = hin + (size_t)t * N_ * 64;
    const float* ab = a_s + (size_t)t * N_ * HEADS;
    float acc = 0.f, acc2 = 0.f, den0 = 0.f, den1 = 0.f;
    for (int base = e0; base < e1; base += 64) {
        int rem = e1 - base; if (rem > 64) rem = 64;
        int s = 0; float p0 = 0.f, p1 = 0.f;
        if (lane < rem) {
            s = cb[base + lane];
            p0 = expf(lrelu(ab[s * HEADS] + ad0));
            if (HEADS == 2) p1 = expf(lrelu(ab[s * HEADS + 1] + ad1));
        }
        den0 += p0; den1 += p1;
        int k = 0;
        for (; k + 1 < rem; k += 2) {
            int s0 = __builtin_amdgcn_readlane(s, k);
            int s1 = __builtin_amdgcn_readlane(s, k + 1);
            float pk0, pk1;
            if (HEADS == 2) {
                float pa0 = rdlane(p0, k), pa1 = rdlane(p0, k + 1);
                float pb0 = rdlane(p1, k), pb1 = rdlane(p1, k + 1);
                pk0 = (lane < 32) ? pa0 : pb0;
                pk1 = (lane < 32) ? pa1 : pb1;
            } else {
                pk0 = rdlane(p0, k); pk1 = rdlane(p0, k + 1);
            }
            acc  = fmaf(pk0, hb[(size_t)s0 * 64 + lane], acc);
            acc2 = fmaf(pk1, hb[(size_t)s1 * 64 + lane], acc2);
        }
        if (k < rem) {
            int s0 = __builtin_amdgcn_readlane(s, k);
            float pk0 = (HEADS == 2) ? ((lane < 32) ? rdlane(p0, k) : rdlane(p1, k))
                                     : rdlane(p0, k);
            acc = fmaf(pk0, hb[(size_t)s0 * 64 + lane], acc);
        }
    }
    acc += acc2;
#pragma unroll
    for (int m = 1; m < 64; m <<= 1) {
        den0 += __shfl_xor(den0, m);
        if (HEADS == 2) den1 += __shfl_xor(den1, m);
    }
    float den = (HEADS == 2) ? ((lane < 32) ? den0 : den1) : den0;
    outp[(size_t)node * 64 + lane] = elu(acc / (den + 1e-16f) + bias[lane]);
}

// ---- layer 2 GEMM: wave-per-row grid-stride; W2 column in 64 VGPRs ----
__global__ __launch_bounds__(256) void k_h2(
    const float* __restrict__ xin, const float* __restrict__ W2,
    const float* __restrict__ as2, const float* __restrict__ ad2,
    float* __restrict__ h2, float* __restrict__ a_s, float* __restrict__ a_d) {
    int lane = threadIdx.x & 63;
    int wid = (blockIdx.x * blockDim.x + threadIdx.x) >> 6;
    int nw = (gridDim.x * blockDim.x) >> 6;
    float w[64];
#pragma unroll
    for (int k = 0; k < 64; ++k) w[k] = W2[k * 64 + lane];
    float asl = as2[lane], adl = ad2[lane];
    float xv = (wid < T_ * N_) ? xin[(size_t)wid * 64 + lane] : 0.f;
    for (int r = wid; r < T_ * N_; r += nw) {
        float xcur = xv;
        int rn = r + nw;
        if (rn < T_ * N_) xv = xin[(size_t)rn * 64 + lane];
        float acc = 0.f;
#pragma unroll
        for (int k = 0; k < 64; ++k) acc = fmaf(rdlane(xcur, k), w[k], acc);
        h2[(size_t)r * 64 + lane] = acc;
        float s = acc * asl, d = acc * adl;
#pragma unroll
        for (int m = 1; m < 64; m <<= 1) { s += __shfl_xor(s, m); d += __shfl_xor(d, m); }
        if (lane == 0) { a_s[r] = s; a_d[r] = d; }
    }
}

// ---- sorted-batch mean-pool over activated node features ----
__global__ void k_pool(const float* __restrict__ hact, const int* __restrict__ batch,
                       float* __restrict__ sums, float* __restrict__ cnt) {
    int wid = (blockIdx.x * blockDim.x + threadIdx.x) >> 6;
    int lane = threadIdx.x & 63;
    const int WPF = (N_ + 63) / 64;
    int t = wid / WPF, w = wid - t * WPF;
    if (t >= T_) return;
    int n0 = w * 64, n1 = min(n0 + 64, N_);
    float acc = 0.f, cacc = 0.f;
    int cur_b = batch[t * N_ + n0];
    for (int n = n0; n < n1; ++n) {
        int b = batch[t * N_ + n];
        if (b != cur_b) {
            atomicAdd(&sums[(t * B_ + cur_b) * 64 + lane], acc);
            if (lane == 0) atomicAdd(&cnt[t * B_ + cur_b], cacc);
            acc = 0.f; cacc = 0.f; cur_b = b;
        }
        acc += hact[(size_t)(t * N_ + n) * 64 + lane];
        cacc += 1.f;
    }
    atomicAdd(&sums[(t * B_ + cur_b) * 64 + lane], acc);
    if (lane == 0) atomicAdd(&cnt[t * B_ + cur_b], cacc);
}

__global__ void k_emb(const float* __restrict__ sums, const float* __restrict__ cnt,
                      float* __restrict__ emb) {
    int idx = blockIdx.x * blockDim.x + threadIdx.x;
    if (idx >= T_ * B_ * 64) return;
    emb[idx] = sums[idx] / fmaxf(cnt[idx >> 6], 1.0f);
}

__global__ void k_gx(const float* __restrict__ emb, const float* __restrict__ Wih,
                     const float* __restrict__ bih, float* __restrict__ gx) {
    int idx = blockIdx.x * blockDim.x + threadIdx.x;
    if (idx >= T_ * B_ * 192) return;
    int tb = idx / 192, g = idx - tb * 192;
    const float* er = emb + tb * 64;
    const float* wr = Wih + g * 64;
    float acc = bih[g];
#pragma unroll
    for (int k = 0; k < 64; ++k) acc = fmaf(er[k], wr[k], acc);
    gx[idx] = acc;
}

// ---- sequential GRU + classifier head (single block); Wh padded stride 65 ----
__global__ __launch_bounds__(1024) void k_gru(
    const float* __restrict__ gx_all, const float* __restrict__ Whh,
    const float* __restrict__ bhh, const float* __restrict__ Wc1,
    const float* __restrict__ bc1, const float* __restrict__ Wc2,
    const float* __restrict__ bc2, float* __restrict__ out) {
    __shared__ float Wh[192 * 65];
    __shared__ float hL[16 * 64];
    __shared__ float gh[16 * 192];
    __shared__ float hid[16 * 32];
    int tid = threadIdx.x;
    for (int i = tid; i < 192 * 64; i += 1024) Wh[(i >> 6) * 65 + (i & 63)] = Whh[i];
    hL[tid] = 0.f;
    __syncthreads();
    for (int t = 0; t < T_; ++t) {
        for (int idx = tid; idx < 16 * 192; idx += 1024) {
            int b = idx / 192, g = idx - b * 192;
            float acc = bhh[g];
            const float* wr = Wh + g * 65;
            const float* hr = hL + b * 64;
#pragma unroll
            for (int k = 0; k < 64; ++k) acc = fmaf(hr[k], wr[k], acc);
            gh[idx] = acc;
        }
        __syncthreads();
        const float* gxt = gx_all + t * 16 * 192;
        {
            int b = tid >> 6, c = tid & 63;
            float xr = gxt[b * 192 + c], xz = gxt[b * 192 + 64 + c], xn = gxt[b * 192 + 128 + c];
            float hr_ = gh[b * 192 + c], hz = gh[b * 192 + 64 + c], hn = gh[b * 192 + 128 + c];
            float r = 1.f / (1.f + expf(-(xr + hr_)));
            float z = 1.f / (1.f + expf(-(xz + hz)));
            float n = tanhf(xn + r * hn);
            hL[tid] = (1.f - z) * n + z * hL[tid];
        }
        __syncthreads();
    }
    for (int idx = tid; idx < 16 * 32; idx += 1024) {
        int b = idx >> 5, j = idx & 31;
        float acc = bc1[j];
#pragma unroll
        for (int k = 0; k < 64; ++k) acc = fmaf(hL[b * 64 + k], Wc1[k * 32 + j], acc);
        hid[idx] = fmaxf(acc, 0.f);
    }
    __syncthreads();
    if (tid < 16) {
        float acc = bc2[0];
#pragma unroll
        for (int k = 0; k < 32; ++k) acc = fmaf(hid[tid * 32 + k], Wc2[k], acc);
        out[tid] = acc;
    }
}

extern "C" void kernel_launch(void* const* d_in, const int* in_sizes, int n_in,
                              void* d_out, int out_size, void* d_ws, size_t ws_size,
                              hipStream_t stream) {
    const float* x   = (const float*)d_in[0];
    const int*   ei  = (const int*)d_in[1];
    const int* batch = (const int*)d_in[2];
    const float* W1  = (const float*)d_in[3];
    const float* as1 = (const float*)d_in[4];
    const float* ad1 = (const float*)d_in[5];
    const float* b1  = (const float*)d_in[6];
    const float* W2  = (const float*)d_in[7];
    const float* as2 = (const float*)d_in[8];
    const float* ad2 = (const float*)d_in[9];
    const float* b2  = (const float*)d_in[10];
    const float* Wih = (const float*)d_in[11];
    const float* Whh = (const float*)d_in[12];
    const float* bih = (const float*)d_in[13];
    const float* bhh = (const float*)d_in[14];
    const float* Wc1 = (const float*)d_in[15];
    const float* bc1 = (const float*)d_in[16];
    const float* Wc2 = (const float*)d_in[17];
    const float* bc2 = (const float*)d_in[18];
    float* out = (float*)d_out;

    float* ws = (float*)d_ws;
    float* hA     = ws;                      // 20,480,000 (h1 / h2)
    float* hX     = hA + 20480000;           // 20,480,000 (activated xin / out2)
    float* a_s    = hX + 20480000;           // 640,000
    float* a_d    = a_s + 640000;            // 640,000
    int*   rowptr = (int*)(a_d + 640000);    // 16*(N+1) -> pad 320,032
    int*   col    = rowptr + 320032;         // 16*EN = 5,440,000
    float* sums   = (float*)(col + 5440000); // 16,384
    float* cnt    = sums + 16384;            // 256
    float* emb    = cnt + 256;               // 16,384
    float* gx     = emb + 16384;             // 49,152
    int*   blkCnt = (int*)(gx + 49152);      // 4096
    int*   blkOff = blkCnt + 4096;           // 4096
    int*   bbase  = blkOff + 4096;           // 513 (+pad)
    // bucket aliases hA: consumed by k_scat2 before k_h1 writes hA
    int*   bucket = (int*)hA;                // 16*E = 5,120,000 ints

    const int BPF_AGG = (N_ + 3) / 4;        // 5000 (4 nodes/block)

    hipMemsetAsync(sums, 0, (size_t)(16384 + 256) * 4, stream);

    // ---- CSR build: single-pass radix partition ----
    k_bcnt<<<16 * CPB, 256, 0, stream>>>(ei, blkCnt);
    k_bscan<<<1, 256, 0, stream>>>(blkCnt, bbase, blkOff);
    k_bfill<<<16 * CPB, 256, 0, stream>>>(ei, blkOff, bucket);
    k_scat2<<<16 * RPF, 256, 0, stream>>>(bucket, bbase, rowptr, col);

    // ---- layer 1 ----
    k_h1<<<1024, 256, 0, stream>>>(x, W1, as1, ad1, hA, a_s, a_d);
    k_agg<2><<<16 * BPF_AGG, 256, 0, stream>>>(rowptr, col, a_s, a_d, hA, b1, hX);

    // ---- layer 2 ----
    k_h2<<<1024, 256, 0, stream>>>(hX, W2, as2, ad2, hA, a_s, a_d);
    k_agg<1><<<16 * BPF_AGG, 256, 0, stream>>>(rowptr, col, a_s, a_d, hA, b2, hX);

    // ---- pool + GRU + head ----
    {
        const int WPF = (N_ + 63) / 64;
        int waves = T_ * WPF;
        k_pool<<<(waves * 64 + 255) / 256, 256, 0, stream>>>(hX, batch, sums, cnt);
    }
    k_emb<<<(T_ * B_ * 64 + 255) / 256, 256, 0, stream>>>(sums, cnt, emb);
    k_gx<<<(T_ * B_ * 192 + 255) / 256, 256, 0, stream>>>(emb, Wih, bih, gx);
    k_gru<<<1, 1024, 0, stream>>>(gx, Whh, bhh, Wc1, bc1, Wc2, bc2, out);
}

// Round 10
// 871.505 us; speedup vs baseline: 1.5590x; 1.1088x over previous
//
#include <hip/hip_runtime.h>
#include <math.h>

#define T_ 16
#define N_ 20000
#define E_ 320000
#define EN_ (E_ + N_)
#define B_ 16
#define RPF 32
#define RNODES (N_ / RPF)        // 625 nodes per range (exact)
#define SLICE_CAP 12544          // mean 10625, sigma~100 -> +19 sigma headroom
#define BCAP 13000               // fixed bucket capacity (+23 sigma)
#define CPB 64                   // chunks per frame for partition pass
#define CHUNK4 (E_ / 4 / CPB)    // 1250 int4 per chunk

__device__ __forceinline__ float lrelu(float v) { return v >= 0.f ? v : 0.2f * v; }
__device__ __forceinline__ float elu(float v) { return v > 0.f ? v : expm1f(v); }
__device__ __forceinline__ float rdlane(float v, int k) {
    return __uint_as_float(__builtin_amdgcn_readlane(__float_as_uint(v), k));
}

__device__ __forceinline__ void frame_map(int bid, int* frame, int* local) {
    int blk = bid >> 3;
    *frame = (bid & 7) * 2 + (blk & 1);
    *local = blk >> 1;
}

// ---- layer 1: h1 = x @ W1 (7->64), per-head attention dots ----
__global__ __launch_bounds__(256) void k_h1(
    const float* __restrict__ x, const float* __restrict__ W1,
    const float* __restrict__ as1, const float* __restrict__ ad1,
    float* __restrict__ h1, float* __restrict__ a_s, float* __restrict__ a_d) {
    int lane = threadIdx.x & 63;
    int wid = (blockIdx.x * blockDim.x + threadIdx.x) >> 6;
    int nw = (gridDim.x * blockDim.x) >> 6;
    float w[7];
#pragma unroll
    for (int k = 0; k < 7; ++k) w[k] = W1[k * 64 + lane];
    float asl = as1[lane], adl = ad1[lane];
    float xv = (wid < T_ * N_ && lane < 7) ? x[(size_t)wid * 7 + lane] : 0.f;
    for (int r = wid; r < T_ * N_; r += nw) {
        float xcur = xv;
        int rn = r + nw;
        if (rn < T_ * N_ && lane < 7) xv = x[(size_t)rn * 7 + lane];
        float acc = 0.f;
#pragma unroll
        for (int k = 0; k < 7; ++k) acc = fmaf(rdlane(xcur, k), w[k], acc);
        h1[(size_t)r * 64 + lane] = acc;
        float s = acc * asl, d = acc * adl;
#pragma unroll
        for (int m = 1; m < 32; m <<= 1) { s += __shfl_xor(s, m); d += __shfl_xor(d, m); }
        if ((lane & 31) == 0) {
            a_s[r * 2 + (lane >> 5)] = s;
            a_d[r * 2 + (lane >> 5)] = d;
        }
    }
}

// ---- partition: per-(frame,chunk) block counts in LDS, reserves runs via one
//      global atomicAdd per range, then scatters packed (dl<<15|src) ----
__global__ __launch_bounds__(256) void k_bfill2(const int* __restrict__ ei,
                                                int* __restrict__ gcur,
                                                int* __restrict__ bucket) {
    int t = blockIdx.x & 15, c = blockIdx.x >> 4;
    __shared__ int cl[RPF];
    __shared__ int rbase[RPF];
    if (threadIdx.x < RPF) cl[threadIdx.x] = 0;
    __syncthreads();
    const int4* db4 = (const int4*)(ei + (size_t)t * 2 * E_ + E_) + c * CHUNK4;
    const int4* sb4 = (const int4*)(ei + (size_t)t * 2 * E_) + c * CHUNK4;
    for (int i = threadIdx.x; i < CHUNK4; i += 256) {
        int4 d = db4[i];
        atomicAdd(&cl[d.x / RNODES], 1);
        atomicAdd(&cl[d.y / RNODES], 1);
        atomicAdd(&cl[d.z / RNODES], 1);
        atomicAdd(&cl[d.w / RNODES], 1);
    }
    __syncthreads();
    if (threadIdx.x < RPF) {
        rbase[threadIdx.x] = atomicAdd(&gcur[t * RPF + threadIdx.x], cl[threadIdx.x]);
        cl[threadIdx.x] = 0;
    }
    __syncthreads();
    for (int i = threadIdx.x; i < CHUNK4; i += 256) {
        int4 d = db4[i];
        int4 s = sb4[i];
        int b, dl, p;
        b = d.x / RNODES; dl = d.x - b * RNODES;
        p = rbase[b] + atomicAdd(&cl[b], 1);
        bucket[(size_t)(t * RPF + b) * BCAP + p] = (dl << 15) | s.x;
        b = d.y / RNODES; dl = d.y - b * RNODES;
        p = rbase[b] + atomicAdd(&cl[b], 1);
        bucket[(size_t)(t * RPF + b) * BCAP + p] = (dl << 15) | s.y;
        b = d.z / RNODES; dl = d.z - b * RNODES;
        p = rbase[b] + atomicAdd(&cl[b], 1);
        bucket[(size_t)(t * RPF + b) * BCAP + p] = (dl << 15) | s.z;
        b = d.w / RNODES; dl = d.w - b * RNODES;
        p = rbase[b] + atomicAdd(&cl[b], 1);
        bucket[(size_t)(t * RPF + b) * BCAP + p] = (dl << 15) | s.w;
    }
}

// ---- per-(frame,range): slice base from shfl-scan of counts; build rowptr
//      span + col slice in LDS; dense flush ----
__global__ __launch_bounds__(256) void k_scat2(const int* __restrict__ bucket,
                                               const int* __restrict__ gcur,
                                               int* __restrict__ rowptr,
                                               int* __restrict__ col) {
    int t = blockIdx.x & 15, rg = blockIdx.x >> 4;
    __shared__ int hist[RNODES];
    __shared__ int cur[RNODES];
    __shared__ int colL[SLICE_CAP];
    __shared__ int wsum[4];
    __shared__ int carryS;
    int tid = threadIdx.x, lane = tid & 63, wv = tid >> 6;
    // slice base = prefix of this frame's range counts + rg*RNODES (self-loop slots)
    int vcnt = (lane < RPF) ? gcur[t * RPF + lane] : 0;
    int sc = vcnt;
#pragma unroll
    for (int off = 1; off < RPF; off <<= 1) {
        int u = __shfl_up(sc, off);
        if (lane >= off) sc += u;
    }
    int cnt = __shfl(vcnt, rg);
    int inclAt = __shfl(sc, rg);
    int sliceBase = (inclAt - cnt) + rg * RNODES;
    int r0 = rg * RNODES;
    const int* bk = bucket + (size_t)(t * RPF + rg) * BCAP;
    bool ovf = (cnt + RNODES) > SLICE_CAP;
    int* rp = rowptr + t * (N_ + 1);
    int* cf = col + (size_t)t * EN_;
    for (int i = tid; i < RNODES; i += 256) hist[i] = 0;
    if (tid == 0) carryS = 0;
    __syncthreads();
    for (int i = tid; i < cnt; i += 256) atomicAdd(&hist[bk[i] >> 15], 1);
    __syncthreads();
    // inclusive scan of (hist[i]+1) -> cur; rowptr span write
    for (int base = 0; base < RNODES; base += 256) {
        int i = base + tid;
        int v = (i < RNODES) ? hist[i] + 1 : 0;
        int s = v;
#pragma unroll
        for (int off = 1; off < 64; off <<= 1) {
            int u = __shfl_up(s, off);
            if (lane >= off) s += u;
        }
        if (lane == 63) wsum[wv] = s;
        __syncthreads();
        if (tid == 0) {
            int a = 0;
#pragma unroll
            for (int w2 = 0; w2 < 4; ++w2) { int x2 = wsum[w2]; wsum[w2] = a; a += x2; }
        }
        __syncthreads();
        int incl = s + wsum[wv] + carryS;
        if (i < RNODES) {
            cur[i] = incl - v;
            rp[r0 + i + 1] = sliceBase + incl;
        }
        __syncthreads();
        if (tid == 255) carryS = incl;
        __syncthreads();
    }
    if (rg == 0 && tid == 0) rp[0] = 0;
    __syncthreads();
    for (int i = tid; i < cnt; i += 256) {
        int e = bk[i];
        int dl = e >> 15, src = e & 0x7FFF;
        int p = atomicAdd(&cur[dl], 1);
        if (ovf) cf[sliceBase + p] = src; else colL[p] = src;
    }
    __syncthreads();
    for (int i = tid; i < RNODES; i += 256) {
        int p = cur[i];
        if (ovf) cf[sliceBase + p] = r0 + i; else colL[p] = r0 + i;
    }
    __syncthreads();
    if (!ovf) {
        int len = cnt + RNODES;
        for (int i = tid; i < len; i += 256) cf[sliceBase + i] = colL[i];
    }
}

// ---- gather-aggregate: wave per (t,node); scalarized loop bounds, 4-edge unroll ----
template <int HEADS>
__global__ __launch_bounds__(256) void k_agg(
    const int* __restrict__ rowptr, const int* __restrict__ col,
    const float* __restrict__ a_s, const float* __restrict__ a_d,
    const float* __restrict__ hin, const float* __restrict__ bias,
    float* __restrict__ outp) {
    int t, local;
    frame_map(blockIdx.x, &t, &local);
    int lane = threadIdx.x & 63;
    int n = local * 4 + (threadIdx.x >> 6);
    if (n >= N_) return;
    int node = t * N_ + n;
    float ad0 = a_d[node * HEADS];
    float ad1 = (HEADS == 2) ? a_d[node * HEADS + 1] : 0.f;
    int e0 = __builtin_amdgcn_readfirstlane(rowptr[t * (N_ + 1) + n]);
    int e1 = __builtin_amdgcn_readfirstlane(rowptr[t * (N_ + 1) + n + 1]);
    const int* cb = col + (size_t)t * EN_;
    const float* hb = hin + (size_t)t * N_ * 64;
    const float* ab = a_s + (size_t)t * N_ * HEADS;
    float acc0 = 0.f, acc1 = 0.f, acc2 = 0.f, acc3 = 0.f, den0 = 0.f, den1 = 0.f;
    for (int base = e0; base < e1; base += 64) {
        int rem = e1 - base; if (rem > 64) rem = 64;
        int s = 0; float p0 = 0.f, p1 = 0.f;
        if (lane < rem) {
            s = cb[base + lane];
            if (HEADS == 2) {
                float2 av = *(const float2*)(ab + s * 2);
                p0 = expf(lrelu(av.x + ad0));
                p1 = expf(lrelu(av.y + ad1));
            } else {
                p0 = expf(lrelu(ab[s] + ad0));
            }
        }
        den0 += p0; den1 += p1;
        int k = 0;
        for (; k + 4 <= rem; k += 4) {
            int sa = __builtin_amdgcn_readlane(s, k);
            int sb = __builtin_amdgcn_readlane(s, k + 1);
            int sc = __builtin_amdgcn_readlane(s, k + 2);
            int sd = __builtin_amdgcn_readlane(s, k + 3);
            float pa, pb, pc, pd;
            if (HEADS == 2) {
                pa = (lane < 32) ? rdlane(p0, k) : rdlane(p1, k);
                pb = (lane < 32) ? rdlane(p0, k + 1) : rdlane(p1, k + 1);
                pc = (lane < 32) ? rdlane(p0, k + 2) : rdlane(p1, k + 2);
                pd = (lane < 32) ? rdlane(p0, k + 3) : rdlane(p1, k + 3);
            } else {
                pa = rdlane(p0, k); pb = rdlane(p0, k + 1);
                pc = rdlane(p0, k + 2); pd = rdlane(p0, k + 3);
            }
            acc0 = fmaf(pa, hb[((size_t)sa << 6) + lane], acc0);
            acc1 = fmaf(pb, hb[((size_t)sb << 6) + lane], acc1);
            acc2 = fmaf(pc, hb[((size_t)sc << 6) + lane], acc2);
            acc3 = fmaf(pd, hb[((size_t)sd << 6) + lane], acc3);
        }
        for (; k < rem; ++k) {
            int sa = __builtin_amdgcn_readlane(s, k);
            float pa = (HEADS == 2) ? ((lane < 32) ? rdlane(p0, k) : rdlane(p1, k))
                                    : rdlane(p0, k);
            acc0 = fmaf(pa, hb[((size_t)sa << 6) + lane], acc0);
        }
    }
    float acc = (acc0 + acc1) + (acc2 + acc3);
#pragma unroll
    for (int m = 1; m < 64; m <<= 1) {
        den0 += __shfl_xor(den0, m);
        if (HEADS == 2) den1 += __shfl_xor(den1, m);
    }
    float den = (HEADS == 2) ? ((lane < 32) ? den0 : den1) : den0;
    outp[(size_t)node * 64 + lane] = elu(acc / (den + 1e-16f) + bias[lane]);
}

// ---- layer 2 GEMM: wave-per-row grid-stride; W2 column in 64 VGPRs ----
__global__ __launch_bounds__(256) void k_h2(
    const float* __restrict__ xin, const float* __restrict__ W2,
    const float* __restrict__ as2, const float* __restrict__ ad2,
    float* __restrict__ h2, float* __restrict__ a_s, float* __restrict__ a_d) {
    int lane = threadIdx.x & 63;
    int wid = (blockIdx.x * blockDim.x + threadIdx.x) >> 6;
    int nw = (gridDim.x * blockDim.x) >> 6;
    float w[64];
#pragma unroll
    for (int k = 0; k < 64; ++k) w[k] = W2[k * 64 + lane];
    float asl = as2[lane], adl = ad2[lane];
    float xv = (wid < T_ * N_) ? xin[(size_t)wid * 64 + lane] : 0.f;
    for (int r = wid; r < T_ * N_; r += nw) {
        float xcur = xv;
        int rn = r + nw;
        if (rn < T_ * N_) xv = xin[(size_t)rn * 64 + lane];
        float acc = 0.f;
#pragma unroll
        for (int k = 0; k < 64; ++k) acc = fmaf(rdlane(xcur, k), w[k], acc);
        h2[(size_t)r * 64 + lane] = acc;
        float s = acc * asl, d = acc * adl;
#pragma unroll
        for (int m = 1; m < 64; m <<= 1) { s += __shfl_xor(s, m); d += __shfl_xor(d, m); }
        if (lane == 0) { a_s[r] = s; a_d[r] = d; }
    }
}

// ---- sorted-batch mean-pool over activated node features ----
__global__ void k_pool(const float* __restrict__ hact, const int* __restrict__ batch,
                       float* __restrict__ sums, float* __restrict__ cnt) {
    int wid = (blockIdx.x * blockDim.x + threadIdx.x) >> 6;
    int lane = threadIdx.x & 63;
    const int WPF = (N_ + 63) / 64;
    int t = wid / WPF, w = wid - t * WPF;
    if (t >= T_) return;
    int n0 = w * 64, n1 = min(n0 + 64, N_);
    float acc = 0.f, cacc = 0.f;
    int cur_b = batch[t * N_ + n0];
    for (int n = n0; n < n1; ++n) {
        int b = batch[t * N_ + n];
        if (b != cur_b) {
            atomicAdd(&sums[(t * B_ + cur_b) * 64 + lane], acc);
            if (lane == 0) atomicAdd(&cnt[t * B_ + cur_b], cacc);
            acc = 0.f; cacc = 0.f; cur_b = b;
        }
        acc += hact[(size_t)(t * N_ + n) * 64 + lane];
        cacc += 1.f;
    }
    atomicAdd(&sums[(t * B_ + cur_b) * 64 + lane], acc);
    if (lane == 0) atomicAdd(&cnt[t * B_ + cur_b], cacc);
}

__global__ void k_emb(const float* __restrict__ sums, const float* __restrict__ cnt,
                      float* __restrict__ emb) {
    int idx = blockIdx.x * blockDim.x + threadIdx.x;
    if (idx >= T_ * B_ * 64) return;
    emb[idx] = sums[idx] / fmaxf(cnt[idx >> 6], 1.0f);
}

__global__ void k_gx(const float* __restrict__ emb, const float* __restrict__ Wih,
                     const float* __restrict__ bih, float* __restrict__ gx) {
    int idx = blockIdx.x * blockDim.x + threadIdx.x;
    if (idx >= T_ * B_ * 192) return;
    int tb = idx / 192, g = idx - tb * 192;
    const float* er = emb + tb * 64;
    const float* wr = Wih + g * 64;
    float acc = bih[g];
#pragma unroll
    for (int k = 0; k < 64; ++k) acc = fmaf(er[k], wr[k], acc);
    gx[idx] = acc;
}

// ---- sequential GRU + classifier head (single block); Wh padded stride 65 ----
__global__ __launch_bounds__(1024) void k_gru(
    const float* __restrict__ gx_all, const float* __restrict__ Whh,
    const float* __restrict__ bhh, const float* __restrict__ Wc1,
    const float* __restrict__ bc1, const float* __restrict__ Wc2,
    const float* __restrict__ bc2, float* __restrict__ out) {
    __shared__ float Wh[192 * 65];
    __shared__ float hL[16 * 64];
    __shared__ float gh[16 * 192];
    __shared__ float hid[16 * 32];
    int tid = threadIdx.x;
    for (int i = tid; i < 192 * 64; i += 1024) Wh[(i >> 6) * 65 + (i & 63)] = Whh[i];
    hL[tid] = 0.f;
    __syncthreads();
    for (int t = 0; t < T_; ++t) {
        for (int idx = tid; idx < 16 * 192; idx += 1024) {
            int b = idx / 192, g = idx - b * 192;
            float acc = bhh[g];
            const float* wr = Wh + g * 65;
            const float* hr = hL + b * 64;
#pragma unroll
            for (int k = 0; k < 64; ++k) acc = fmaf(hr[k], wr[k], acc);
            gh[idx] = acc;
        }
        __syncthreads();
        const float* gxt = gx_all + t * 16 * 192;
        {
            int b = tid >> 6, c = tid & 63;
            float xr = gxt[b * 192 + c], xz = gxt[b * 192 + 64 + c], xn = gxt[b * 192 + 128 + c];
            float hr_ = gh[b * 192 + c], hz = gh[b * 192 + 64 + c], hn = gh[b * 192 + 128 + c];
            float r = 1.f / (1.f + expf(-(xr + hr_)));
            float z = 1.f / (1.f + expf(-(xz + hz)));
            float n = tanhf(xn + r * hn);
            hL[tid] = (1.f - z) * n + z * hL[tid];
        }
        __syncthreads();
    }
    for (int idx = tid; idx < 16 * 32; idx += 1024) {
        int b = idx >> 5, j = idx & 31;
        float acc = bc1[j];
#pragma unroll
        for (int k = 0; k < 64; ++k) acc = fmaf(hL[b * 64 + k], Wc1[k * 32 + j], acc);
        hid[idx] = fmaxf(acc, 0.f);
    }
    __syncthreads();
    if (tid < 16) {
        float acc = bc2[0];
#pragma unroll
        for (int k = 0; k < 32; ++k) acc = fmaf(hid[tid * 32 + k], Wc2[k], acc);
        out[tid] = acc;
    }
}

extern "C" void kernel_launch(void* const* d_in, const int* in_sizes, int n_in,
                              void* d_out, int out_size, void* d_ws, size_t ws_size,
                              hipStream_t stream) {
    const float* x   = (const float*)d_in[0];
    const int*   ei  = (const int*)d_in[1];
    const int* batch = (const int*)d_in[2];
    const float* W1  = (const float*)d_in[3];
    const float* as1 = (const float*)d_in[4];
    const float* ad1 = (const float*)d_in[5];
    const float* b1  = (const float*)d_in[6];
    const float* W2  = (const float*)d_in[7];
    const float* as2 = (const float*)d_in[8];
    const float* ad2 = (const float*)d_in[9];
    const float* b2  = (const float*)d_in[10];
    const float* Wih = (const float*)d_in[11];
    const float* Whh = (const float*)d_in[12];
    const float* bih = (const float*)d_in[13];
    const float* bhh = (const float*)d_in[14];
    const float* Wc1 = (const float*)d_in[15];
    const float* bc1 = (const float*)d_in[16];
    const float* Wc2 = (const float*)d_in[17];
    const float* bc2 = (const float*)d_in[18];
    float* out = (float*)d_out;

    float* ws = (float*)d_ws;
    float* hA     = ws;                      // 20,480,000 (h1 / h2)
    float* hX     = hA + 20480000;           // 20,480,000 (activated xin / out2)
    float* a_s    = hX + 20480000;           // 640,000
    float* a_d    = a_s + 640000;            // 640,000
    int*   rowptr = (int*)(a_d + 640000);    // 16*(N+1) -> pad 320,032
    int*   col    = rowptr + 320032;         // 16*EN = 5,440,000
    float* sums   = (float*)(col + 5440000); // 16,384
    float* cnt    = sums + 16384;            // 256
    float* emb    = cnt + 256;               // 16,384
    float* gx     = emb + 16384;             // 49,152
    int*   gcur   = (int*)(gx + 49152);      // 512 (+pad)
    // bucket aliases hA: consumed by k_scat2 before k_h1 writes hA
    int*   bucket = (int*)hA;                // 512*BCAP = 6,656,000 ints < 20.48M

    const int BPF_AGG = (N_ + 3) / 4;        // 5000 (4 nodes/block)

    hipMemsetAsync(gcur, 0, (size_t)512 * 4, stream);
    hipMemsetAsync(sums, 0, (size_t)(16384 + 256) * 4, stream);

    // ---- CSR build: block-reserved radix partition (2 kernels) ----
    k_bfill2<<<16 * CPB, 256, 0, stream>>>(ei, gcur, bucket);
    k_scat2<<<16 * RPF, 256, 0, stream>>>(bucket, gcur, rowptr, col);

    // ---- layer 1 ----
    k_h1<<<1024, 256, 0, stream>>>(x, W1, as1, ad1, hA, a_s, a_d);
    k_agg<2><<<16 * BPF_AGG, 256, 0, stream>>>(rowptr, col, a_s, a_d, hA, b1, hX);

    // ---- layer 2 ----
    k_h2<<<1024, 256, 0, stream>>>(hX, W2, as2, ad2, hA, a_s, a_d);
    k_agg<1><<<16 * BPF_AGG, 256, 0, stream>>>(rowptr, col, a_s, a_d, hA, b2, hX);

    // ---- pool + GRU + head ----
    {
        const int WPF = (N_ + 63) / 64;
        int waves = T_ * WPF;
        k_pool<<<(waves * 64 + 255) / 256, 256, 0, stream>>>(hX, batch, sums, cnt);
    }
    k_emb<<<(T_ * B_ * 64 + 255) / 256, 256, 0, stream>>>(sums, cnt, emb);
    k_gx<<<(T_ * B_ * 192 + 255) / 256, 256, 0, stream>>>(emb, Wih, bih, gx);
    k_gru<<<1, 1024, 0, stream>>>(gx, Whh, bhh, Wc1, bc1, Wc2, bc2, out);
}